// Round 1
// baseline (127.411 us; speedup 1.0000x reference)
//
#include <hip/hip_runtime.h>

// x (B,I); w/s/t (O,I); out (B,O), all fp32.
#define B_SZ 256
#define O_SZ 1024
#define I_SZ 1024

#define TB   8     // b rows per block (LDS x tile)
#define SLN  32    // lanes per half splitting i
#define KITERS (I_SZ / (SLN * 4))   // 8
#define ISTEP  (SLN * 4)            // 128
#define OITER  4                    // o-groups per block (32 o's/block)

typedef float v2f __attribute__((ext_vector_type(2)));

// out[b,o] = sum_i w[o,i]*phi((x[b,i]-t[o,i])/s[o,i]),  phi(z) = -z*exp(-0.5 z^2)
// u = K*(x-t)/s, K = sqrt(0.5*log2 e) -> exp2(-u^2) = exp(-z^2/2);  w*z = u*(w/K)
//
// R10 theory: dispatch 56.7us vs trans-pipe floor ~30.7us (268M v_exp_f32 @~16cyc
// + 33.5M rcp) -> 54% trans utilization, while packed-VALU pipe holds only ~11us
// of work. Split the exp2 load 50/50: cp0 keeps v_exp_f32 (trans pipe), cp1 uses
// a packed-VALU polynomial exp2 (round-trick range reduction + Horner-5 +
// integer exponent splice). New floors: trans ~17us, packed VALU ~20us, LDS ~20us.
// Predicted dispatch ~38-45us.
// Register discipline (R4/R5/R7/R8 spills): inner body keeps the 44-VGPR
// structure; poly temps are block-local; oi-loop pinned unroll 1.

static __device__ __forceinline__ float exp2splice(float t, float p) {
    // t = m + 1.5*2^23  (bits = 0x4B400000 + n, n = rint(m), n in [-126,0])
    // result bits = p_bits + (n << 23)   [(t_bits<<23) == (n<<23) mod 2^32]
    return __builtin_bit_cast(float,
        (__builtin_bit_cast(int, t) << 23) + __builtin_bit_cast(int, p));
}

__launch_bounds__(256, 4)
__global__ void wavkan_dog_kernel(const float* __restrict__ X,
                                  const float* __restrict__ W,
                                  const float* __restrict__ S,
                                  const float* __restrict__ T,
                                  float* __restrict__ Out) {
    const int tid  = threadIdx.x;
    const int wave = tid >> 6;
    const int lane = tid & 63;
    const int half = lane >> 5;
    const int sl   = lane & (SLN - 1);

    const int obase = blockIdx.x * (8 * OITER) + wave * 2 + half; // + oi*8
    const int b0    = blockIdx.y * TB;

    __shared__ __align__(16) float xls[TB * I_SZ];     // 32 KB

    const int r0 = obase * I_SZ + sl * 4;  // 32-bit offsets, same for W/S/T
    const float* wr = W + r0;
    const float* sr = S + r0;
    const float* tr = T + r0;

    // Issue first w/s/t prefetch BEFORE the LDS fill so it flies under the barrier.
    float4 sN = *(const float4*)(sr);
    float4 tN = *(const float4*)(tr);
    float4 wN = *(const float4*)(wr);

    {   // cooperative fill: x[b0:b0+8][:] is one contiguous 32 KB span
        const float4* Xg4 = (const float4*)(X + (size_t)b0 * I_SZ);
        float4* L4 = (float4*)xls;
#pragma unroll
        for (int p = 0; p < (TB * I_SZ / 4) / 256; ++p)
            L4[tid + p * 256] = Xg4[tid + p * 256];
    }
    __syncthreads();

    const float K  = 0.84932180028801904272f;  // sqrt(0.5 * log2 e)
    const float iK = 1.17741002251547469101f;  // 1/K
    const float* xb = xls + sl * 4;

    // exp2 poly coefficients (Taylor of 2^f on [-0.5,0.5], rel err ~2.4e-6)
    const float C0 = 1.0f;
    const float C1 = 0.69314718056f;
    const float C2 = 0.24022650696f;
    const float C3 = 0.05550410866f;
    const float C4 = 0.00961812911f;
    const float C5 = 0.00133335581f;
    const float RND = 12582912.0f;             // 1.5 * 2^23

#pragma unroll 1
    for (int oi = 0; oi < OITER; ++oi) {
        const int ob = oi * 8 * I_SZ;          // element offset to this o-group's rows

        v2f acc[TB];
#pragma unroll
        for (int j = 0; j < TB; ++j) acc[j] = (v2f)(0.0f);

#pragma unroll 2
        for (int k = 0; k < KITERS; ++k) {
            const int i = k * ISTEP;
            // prefetch k+1; at k==7 prefetch the NEXT o-group's k=0 (wraps to oi=0: L1-hot, harmless)
            const int in = (k < KITERS - 1) ? (ob + (k + 1) * ISTEP)
                                            : ((((oi + 1) & (OITER - 1)) * 8) * I_SZ);

            const float4 s4 = sN, t4 = tN, w4 = wN;
            sN = *(const float4*)(sr + in);
            tN = *(const float4*)(tr + in);
            wN = *(const float4*)(wr + in);

            v2f rk[2], tkn[2], wk[2];
            {
                const float* sa = (const float*)&s4;
                const float* ta = (const float*)&t4;
                const float* wa = (const float*)&w4;
#pragma unroll
                for (int cp = 0; cp < 2; ++cp) {
                    const v2f r  = { __builtin_amdgcn_rcpf(sa[2*cp]),
                                     __builtin_amdgcn_rcpf(sa[2*cp+1]) };
                    const v2f tt = { ta[2*cp], ta[2*cp+1] };
                    const v2f ww = { wa[2*cp], wa[2*cp+1] };
                    rk[cp]  = r * K;
                    tkn[cp] = -(tt * rk[cp]);
                    wk[cp]  = ww * iK;
                }
            }

#pragma unroll
            for (int j = 0; j < TB; ++j) {
                const float4 xv = *(const float4*)(xb + j * I_SZ + i); // ds_read_b128, imm offset
                const float* xp = (const float*)&xv;

                // ---- cp 0: trans-pipe exp2 ----
                {
                    const v2f x2 = { xp[0], xp[1] };
                    const v2f u  = __builtin_elementwise_fma(x2, rk[0], tkn[0]); // z*K
                    const v2f m  = u * (-u);                                     // -(z*K)^2
                    v2f e;
                    e.x = __builtin_amdgcn_exp2f(m.x);                           // exp(-z^2/2)
                    e.y = __builtin_amdgcn_exp2f(m.y);
                    const v2f y = u * wk[0];                                     // w*z
                    acc[j] = __builtin_elementwise_fma(-y, e, acc[j]);           // += -w*z*e
                }

                // ---- cp 1: packed-VALU polynomial exp2 ----
                {
                    const v2f x2 = { xp[2], xp[3] };
                    const v2f u  = __builtin_elementwise_fma(x2, rk[1], tkn[1]);
                    const v2f m  = u * (-u);
                    const v2f mc = __builtin_elementwise_max(m, (v2f)(-126.0f));
                    const v2f tb = mc + (v2f)(RND);     // rint via round-trick
                    const v2f nf = tb - (v2f)(RND);
                    const v2f fr = mc - nf;             // in [-0.5, 0.5]
                    v2f p = __builtin_elementwise_fma(fr, (v2f)(C5), (v2f)(C4));
                    p = __builtin_elementwise_fma(fr, p, (v2f)(C3));
                    p = __builtin_elementwise_fma(fr, p, (v2f)(C2));
                    p = __builtin_elementwise_fma(fr, p, (v2f)(C1));
                    p = __builtin_elementwise_fma(fr, p, (v2f)(C0));
                    v2f e;
                    e.x = exp2splice(tb.x, p.x);        // 2^n * poly, int exponent add
                    e.y = exp2splice(tb.y, p.y);
                    const v2f y = u * wk[1];
                    acc[j] = __builtin_elementwise_fma(-y, e, acc[j]);
                }
            }
        }

        // collapse pairs, reduce across the 32 i-split lanes
        float r[TB];
#pragma unroll
        for (int j = 0; j < TB; ++j) r[j] = acc[j].x + acc[j].y;
#pragma unroll
        for (int m = 1; m < SLN; m <<= 1)
#pragma unroll
            for (int j = 0; j < TB; ++j)
                r[j] += __shfl_xor(r[j], m, 64);

        if (sl < TB) {
            float v = 0.0f;
#pragma unroll
            for (int j = 0; j < TB; ++j)
                if (sl == j) v = r[j];
            Out[(size_t)(b0 + sl) * O_SZ + (obase + oi * 8)] = v;
        }
    }
}

extern "C" void kernel_launch(void* const* d_in, const int* in_sizes, int n_in,
                              void* d_out, int out_size, void* d_ws, size_t ws_size,
                              hipStream_t stream) {
    const float* x = (const float*)d_in[0];   // (B, I)
    const float* w = (const float*)d_in[1];   // (O, I)
    const float* s = (const float*)d_in[2];   // (O, I)
    const float* t = (const float*)d_in[3];   // (O, I)
    float* out = (float*)d_out;               // (B, O)

    dim3 grid(O_SZ / (8 * OITER), B_SZ / TB); // (32, 32) = 1024 blocks = 4/CU resident
    wavkan_dog_kernel<<<grid, 256, 0, stream>>>(x, w, s, t, out);
}

// Round 2
// 113.542 us; speedup vs baseline: 1.1221x; 1.1221x over previous
//
#include <hip/hip_runtime.h>

// x (B,I); w/s/t (O,I); out (B,O), all fp32.
#define B_SZ 256
#define O_SZ 1024
#define I_SZ 1024

#define TB   8     // b rows per block (LDS x tile)
#define SLN  32    // lanes per half splitting i
#define KITERS (I_SZ / (SLN * 4))   // 8
#define ISTEP  (SLN * 4)            // 128
#define OITER  2                    // o-groups per block (32 o's/block, 16 o's/group)
#define NTHR 512

typedef float v2f __attribute__((ext_vector_type(2)));

// out[b,o] = sum_i w[o,i]*phi((x[b,i]-t[o,i])/s[o,i]),  phi(z) = -z*exp(-0.5 z^2)
// u = K*(x-t)/s, K = sqrt(0.5*log2 e) -> exp2(-u^2) = exp(-z^2/2);  w*z = u*(w/K)
//
// R10 post-mortem: poly-exp2 split REGRESSED (56.7->75.4us, busy cycles up 82K->119K
// per SIMD). The SIMD is issue-port-bound: wave64 v_exp_f32 blocks the single issue
// port ~16 cyc, so trans and VALU work are additive. Instruction-mix floor:
// 4096 exp x 16cyc + ~16K VALU cyc ~= 82K cyc/SIMD ~= 34us. R9's remaining 40%
// was issue IDLE (dependency/LDS stalls) at only 4 waves/SIMD.
// R11: revert poly; raise occupancy 4->8 waves/SIMD: 512-thread blocks (8 waves),
// TB=8 kept (rcp/prep amortization unchanged), OITER=2, grid (32,32)=1024 blocks
// = 4/CU x 8 waves = 32 waves/CU, LDS 128KB/CU. Predicted 40-47us, VALUBusy 75-85%.
// Register discipline (R4/R5/R7/R8 spills): inner body is R9's proven 44-VGPR
// structure; oi-loop pinned unroll 1; launch_bounds(512,8) caps at 64 VGPR.
__launch_bounds__(NTHR, 8)
__global__ void wavkan_dog_kernel(const float* __restrict__ X,
                                  const float* __restrict__ W,
                                  const float* __restrict__ S,
                                  const float* __restrict__ T,
                                  float* __restrict__ Out) {
    const int tid  = threadIdx.x;
    const int wave = tid >> 6;
    const int lane = tid & 63;
    const int half = lane >> 5;
    const int sl   = lane & (SLN - 1);

    const int obase = blockIdx.x * (16 * OITER) + wave * 2 + half; // + oi*16
    const int b0    = blockIdx.y * TB;

    __shared__ __align__(16) float xls[TB * I_SZ];     // 32 KB

    const int r0 = obase * I_SZ + sl * 4;  // 32-bit offsets, same for W/S/T
    const float* wr = W + r0;
    const float* sr = S + r0;
    const float* tr = T + r0;

    // Issue first w/s/t prefetch BEFORE the LDS fill so it flies under the barrier.
    float4 sN = *(const float4*)(sr);
    float4 tN = *(const float4*)(tr);
    float4 wN = *(const float4*)(wr);

    {   // cooperative fill: x[b0:b0+8][:] is one contiguous 32 KB span
        const float4* Xg4 = (const float4*)(X + (size_t)b0 * I_SZ);
        float4* L4 = (float4*)xls;
#pragma unroll
        for (int p = 0; p < (TB * I_SZ / 4) / NTHR; ++p)
            L4[tid + p * NTHR] = Xg4[tid + p * NTHR];
    }
    __syncthreads();

    const float K  = 0.84932180028801904272f;  // sqrt(0.5 * log2 e)
    const float iK = 1.17741002251547469101f;  // 1/K
    const float* xb = xls + sl * 4;

#pragma unroll 1
    for (int oi = 0; oi < OITER; ++oi) {
        const int ob = oi * 16 * I_SZ;         // element offset to this o-group's rows

        v2f acc[TB];
#pragma unroll
        for (int j = 0; j < TB; ++j) acc[j] = (v2f)(0.0f);

#pragma unroll 2
        for (int k = 0; k < KITERS; ++k) {
            const int i = k * ISTEP;
            // prefetch k+1; at k==7 prefetch the NEXT o-group's k=0 (wraps to oi=0: L1-hot, harmless)
            const int in = (k < KITERS - 1) ? (ob + (k + 1) * ISTEP)
                                            : ((((oi + 1) & (OITER - 1)) * 16) * I_SZ);

            const float4 s4 = sN, t4 = tN, w4 = wN;
            sN = *(const float4*)(sr + in);
            tN = *(const float4*)(tr + in);
            wN = *(const float4*)(wr + in);

            v2f rk[2], tkn[2], wk[2];
            {
                const float* sa = (const float*)&s4;
                const float* ta = (const float*)&t4;
                const float* wa = (const float*)&w4;
#pragma unroll
                for (int cp = 0; cp < 2; ++cp) {
                    const v2f r  = { __builtin_amdgcn_rcpf(sa[2*cp]),
                                     __builtin_amdgcn_rcpf(sa[2*cp+1]) };
                    const v2f tt = { ta[2*cp], ta[2*cp+1] };
                    const v2f ww = { wa[2*cp], wa[2*cp+1] };
                    rk[cp]  = r * K;
                    tkn[cp] = -(tt * rk[cp]);
                    wk[cp]  = ww * iK;
                }
            }

#pragma unroll
            for (int j = 0; j < TB; ++j) {
                const float4 xv = *(const float4*)(xb + j * I_SZ + i); // ds_read_b128, imm offset
                const float* xp = (const float*)&xv;
#pragma unroll
                for (int cp = 0; cp < 2; ++cp) {
                    const v2f x2 = { xp[2*cp], xp[2*cp+1] };
                    const v2f u  = __builtin_elementwise_fma(x2, rk[cp], tkn[cp]); // z*K
                    const v2f m  = u * (-u);                                      // -(z*K)^2
                    v2f e;
                    e.x = __builtin_amdgcn_exp2f(m.x);                            // exp(-z^2/2)
                    e.y = __builtin_amdgcn_exp2f(m.y);
                    const v2f y = u * wk[cp];                                     // w*z
                    acc[j] = __builtin_elementwise_fma(-y, e, acc[j]);            // += -w*z*e
                }
            }
        }

        // collapse pairs, reduce across the 32 i-split lanes
        float r[TB];
#pragma unroll
        for (int j = 0; j < TB; ++j) r[j] = acc[j].x + acc[j].y;
#pragma unroll
        for (int m = 1; m < SLN; m <<= 1)
#pragma unroll
            for (int j = 0; j < TB; ++j)
                r[j] += __shfl_xor(r[j], m, 64);

        if (sl < TB) {
            float v = 0.0f;
#pragma unroll
            for (int j = 0; j < TB; ++j)
                if (sl == j) v = r[j];
            Out[(size_t)(b0 + sl) * O_SZ + (obase + oi * 16)] = v;
        }
    }
}

extern "C" void kernel_launch(void* const* d_in, const int* in_sizes, int n_in,
                              void* d_out, int out_size, void* d_ws, size_t ws_size,
                              hipStream_t stream) {
    const float* x = (const float*)d_in[0];   // (B, I)
    const float* w = (const float*)d_in[1];   // (O, I)
    const float* s = (const float*)d_in[2];   // (O, I)
    const float* t = (const float*)d_in[3];   // (O, I)
    float* out = (float*)d_out;               // (B, O)

    dim3 grid(O_SZ / (16 * OITER), B_SZ / TB); // (32, 32) = 1024 blocks = 4/CU x 8 waves
    wavkan_dog_kernel<<<grid, NTHR, 0, stream>>>(x, w, s, t, out);
}

// Round 3
// 112.195 us; speedup vs baseline: 1.1356x; 1.0120x over previous
//
#include <hip/hip_runtime.h>

// x (B,I); w/s/t (O,I); out (B,O), all fp32.
#define B_SZ 256
#define O_SZ 1024
#define I_SZ 1024

#define TB   4     // b rows per block (LDS x tile) -- halved vs R9 for 8 blocks/CU
#define SLN  32    // lanes per half splitting i
#define KITERS (I_SZ / (SLN * 4))   // 8
#define ISTEP  (SLN * 4)            // 128
#define OITER  4                    // o-groups per block (32 o's/block)
#define NTHR 256

typedef float v2f __attribute__((ext_vector_type(2)));

// out[b,o] = sum_i w[o,i]*phi((x[b,i]-t[o,i])/s[o,i]),  phi(z) = -z*exp(-0.5 z^2)
// u = K*(x-t)/s, K = sqrt(0.5*log2 e) -> exp2(-u^2) = exp(-z^2/2);  w*z = u*(w/K)
//
// R11 post-mortem: launch_bounds(512,8) forced a 32-VGPR body with scratch spills
// (FETCH 10->36MB, WRITE 1->30MB) -- occupancy rose 30->53% but spill waits ate it
// (59.4us). Occupancy theory NOT cleanly tested. R12: same goal, spill-free route:
// keep the proven 256-thread compile shape, halve the x tile (TB=4, 16KB LDS) ->
// 8 blocks/CU x 16KB = 128KB, 32 waves/CU, grid (32,64)=2048 blocks resident in
// one shot. Cost: prep (rcp, rk/tkn/wk) amortizes over 4 rows not 8 -> +~9K
// cyc/SIMD busy (+4us). acc array halves -> ~40 VGPR, under the 64 cap for 8
// waves/EU. Validity gate: FETCH ~13-20MB, WRITE ~1.2MB (no spill traffic).
// Predicted: 40-46us if idle was occupancy-curable; ~55us unchanged => structural
// trans-pipe/clock ceiling (then: precompute rk/tkn/wk into d_ws to cut prep).
__launch_bounds__(NTHR, 8)
__global__ void wavkan_dog_kernel(const float* __restrict__ X,
                                  const float* __restrict__ W,
                                  const float* __restrict__ S,
                                  const float* __restrict__ T,
                                  float* __restrict__ Out) {
    const int tid  = threadIdx.x;
    const int wave = tid >> 6;
    const int lane = tid & 63;
    const int half = lane >> 5;
    const int sl   = lane & (SLN - 1);

    const int obase = blockIdx.x * (8 * OITER) + wave * 2 + half; // + oi*8
    const int b0    = blockIdx.y * TB;

    __shared__ __align__(16) float xls[TB * I_SZ];     // 16 KB

    const int r0 = obase * I_SZ + sl * 4;  // 32-bit offsets, same for W/S/T
    const float* wr = W + r0;
    const float* sr = S + r0;
    const float* tr = T + r0;

    // Issue first w/s/t prefetch BEFORE the LDS fill so it flies under the barrier.
    float4 sN = *(const float4*)(sr);
    float4 tN = *(const float4*)(tr);
    float4 wN = *(const float4*)(wr);

    {   // cooperative fill: x[b0:b0+4][:] is one contiguous 16 KB span
        const float4* Xg4 = (const float4*)(X + (size_t)b0 * I_SZ);
        float4* L4 = (float4*)xls;
#pragma unroll
        for (int p = 0; p < (TB * I_SZ / 4) / NTHR; ++p)
            L4[tid + p * NTHR] = Xg4[tid + p * NTHR];
    }
    __syncthreads();

    const float K  = 0.84932180028801904272f;  // sqrt(0.5 * log2 e)
    const float iK = 1.17741002251547469101f;  // 1/K
    const float* xb = xls + sl * 4;

#pragma unroll 1
    for (int oi = 0; oi < OITER; ++oi) {
        const int ob = oi * 8 * I_SZ;          // element offset to this o-group's rows

        v2f acc[TB];
#pragma unroll
        for (int j = 0; j < TB; ++j) acc[j] = (v2f)(0.0f);

#pragma unroll 2
        for (int k = 0; k < KITERS; ++k) {
            const int i = k * ISTEP;
            // prefetch k+1; at k==7 prefetch the NEXT o-group's k=0 (wraps to oi=0: L1-hot, harmless)
            const int in = (k < KITERS - 1) ? (ob + (k + 1) * ISTEP)
                                            : ((((oi + 1) & (OITER - 1)) * 8) * I_SZ);

            const float4 s4 = sN, t4 = tN, w4 = wN;
            sN = *(const float4*)(sr + in);
            tN = *(const float4*)(tr + in);
            wN = *(const float4*)(wr + in);

            v2f rk[2], tkn[2], wk[2];
            {
                const float* sa = (const float*)&s4;
                const float* ta = (const float*)&t4;
                const float* wa = (const float*)&w4;
#pragma unroll
                for (int cp = 0; cp < 2; ++cp) {
                    const v2f r  = { __builtin_amdgcn_rcpf(sa[2*cp]),
                                     __builtin_amdgcn_rcpf(sa[2*cp+1]) };
                    const v2f tt = { ta[2*cp], ta[2*cp+1] };
                    const v2f ww = { wa[2*cp], wa[2*cp+1] };
                    rk[cp]  = r * K;
                    tkn[cp] = -(tt * rk[cp]);
                    wk[cp]  = ww * iK;
                }
            }

#pragma unroll
            for (int j = 0; j < TB; ++j) {
                const float4 xv = *(const float4*)(xb + j * I_SZ + i); // ds_read_b128, imm offset
                const float* xp = (const float*)&xv;
#pragma unroll
                for (int cp = 0; cp < 2; ++cp) {
                    const v2f x2 = { xp[2*cp], xp[2*cp+1] };
                    const v2f u  = __builtin_elementwise_fma(x2, rk[cp], tkn[cp]); // z*K
                    const v2f m  = u * (-u);                                      // -(z*K)^2
                    v2f e;
                    e.x = __builtin_amdgcn_exp2f(m.x);                            // exp(-z^2/2)
                    e.y = __builtin_amdgcn_exp2f(m.y);
                    const v2f y = u * wk[cp];                                     // w*z
                    acc[j] = __builtin_elementwise_fma(-y, e, acc[j]);            // += -w*z*e
                }
            }
        }

        // collapse pairs, reduce across the 32 i-split lanes
        float r[TB];
#pragma unroll
        for (int j = 0; j < TB; ++j) r[j] = acc[j].x + acc[j].y;
#pragma unroll
        for (int m = 1; m < SLN; m <<= 1)
#pragma unroll
            for (int j = 0; j < TB; ++j)
                r[j] += __shfl_xor(r[j], m, 64);

        if (sl < TB) {
            float v = 0.0f;
#pragma unroll
            for (int j = 0; j < TB; ++j)
                if (sl == j) v = r[j];
            Out[(size_t)(b0 + sl) * O_SZ + (obase + oi * 8)] = v;
        }
    }
}

extern "C" void kernel_launch(void* const* d_in, const int* in_sizes, int n_in,
                              void* d_out, int out_size, void* d_ws, size_t ws_size,
                              hipStream_t stream) {
    const float* x = (const float*)d_in[0];   // (B, I)
    const float* w = (const float*)d_in[1];   // (O, I)
    const float* s = (const float*)d_in[2];   // (O, I)
    const float* t = (const float*)d_in[3];   // (O, I)
    float* out = (float*)d_out;               // (B, O)

    dim3 grid(O_SZ / (8 * OITER), B_SZ / TB); // (32, 64) = 2048 blocks = 8/CU x 4 waves
    wavkan_dog_kernel<<<grid, NTHR, 0, stream>>>(x, w, s, t, out);
}

// Round 4
// 110.450 us; speedup vs baseline: 1.1536x; 1.0158x over previous
//
#include <hip/hip_runtime.h>

// x (B,I); w/s/t (O,I); out (B,O), all fp32.
#define B_SZ 256
#define O_SZ 1024
#define I_SZ 1024

#define TB   8     // b rows per block (LDS x tile)
#define SLN  32    // lanes per half splitting i
#define KITERS (I_SZ / (SLN * 4))   // 8
#define ISTEP  (SLN * 4)            // 128
#define OITER  4                    // o-groups per block (32 o's/block)
#define NTHR 256

typedef float v2f __attribute__((ext_vector_type(2)));

// out[b,o] = sum_i w[o,i]*phi((x[b,i]-t[o,i])/s[o,i]),  phi(z) = -z*exp(-0.5 z^2)
// u = K*(x-t)/s, K = sqrt(0.5*log2 e) -> exp2(-u^2) = exp(-z^2/2);  w*z = u*(w/K)
//
// R12 post-mortem: doubling occupancy (8 blocks/CU, clean 32-VGPR compile, no
// spills) bought ZERO idle reduction (58.2us vs 56.7). The ~20us idle is not
// TLP-curable -> it is a per-wave dependency stall: the compiler sinks each
// v_exp next to its consumer (register-pressure-minded scheduling), every wave
// stalls ~the trans drain on every exp pair, and all waves stall in lockstep.
// R13: back to the R9 base (TB=8, 4 blocks/CU, best busy floor), restructure
// each (k,cp) into three sched_barrier(0)-pinned passes:
//   pass1: 8x ds_read_b64 + u[j]=fma, me[j]=-u^2   (independent)
//   pass2: 16x v_exp_f32 back-to-back cluster
//   pass3: 8x (y=u*wk; acc=fma(-y,e,acc))
// Each exp gets >=15 exps + 16 pk-ops of independent downstream before its
// consumer -> trans latency covered wave-locally. u/me arrays +32 VGPR (~90
// total, cap 128 at launch_bounds(256,4)). Spill gate: WRITE_SIZE ~1.1MB.
// Predicted: 44-49us if trans drain was the stall; unchanged => port-block
// model confirmed -> next: LDS-table exp.
__launch_bounds__(NTHR, 4)
__global__ void wavkan_dog_kernel(const float* __restrict__ X,
                                  const float* __restrict__ W,
                                  const float* __restrict__ S,
                                  const float* __restrict__ T,
                                  float* __restrict__ Out) {
    const int tid  = threadIdx.x;
    const int wave = tid >> 6;
    const int lane = tid & 63;
    const int half = lane >> 5;
    const int sl   = lane & (SLN - 1);

    const int obase = blockIdx.x * (8 * OITER) + wave * 2 + half; // + oi*8
    const int b0    = blockIdx.y * TB;

    __shared__ __align__(16) float xls[TB * I_SZ];     // 32 KB

    const int r0 = obase * I_SZ + sl * 4;  // 32-bit offsets, same for W/S/T
    const float* wr = W + r0;
    const float* sr = S + r0;
    const float* tr = T + r0;

    // Issue first w/s/t prefetch BEFORE the LDS fill so it flies under the barrier.
    float4 sN = *(const float4*)(sr);
    float4 tN = *(const float4*)(tr);
    float4 wN = *(const float4*)(wr);

    {   // cooperative fill: x[b0:b0+8][:] is one contiguous 32 KB span
        const float4* Xg4 = (const float4*)(X + (size_t)b0 * I_SZ);
        float4* L4 = (float4*)xls;
#pragma unroll
        for (int p = 0; p < (TB * I_SZ / 4) / NTHR; ++p)
            L4[tid + p * NTHR] = Xg4[tid + p * NTHR];
    }
    __syncthreads();

    const float K  = 0.84932180028801904272f;  // sqrt(0.5 * log2 e)
    const float iK = 1.17741002251547469101f;  // 1/K
    const float* xb = xls + sl * 4;

#pragma unroll 1
    for (int oi = 0; oi < OITER; ++oi) {
        const int ob = oi * 8 * I_SZ;          // element offset to this o-group's rows

        v2f acc[TB];
#pragma unroll
        for (int j = 0; j < TB; ++j) acc[j] = (v2f)(0.0f);

#pragma unroll 2
        for (int k = 0; k < KITERS; ++k) {
            const int i = k * ISTEP;
            // prefetch k+1; at k==7 prefetch the NEXT o-group's k=0 (wraps to oi=0: L1-hot, harmless)
            const int in = (k < KITERS - 1) ? (ob + (k + 1) * ISTEP)
                                            : ((((oi + 1) & (OITER - 1)) * 8) * I_SZ);

            const float4 s4 = sN, t4 = tN, w4 = wN;
            sN = *(const float4*)(sr + in);
            tN = *(const float4*)(tr + in);
            wN = *(const float4*)(wr + in);

            v2f rk[2], tkn[2], wk[2];
            {
                const float* sa = (const float*)&s4;
                const float* ta = (const float*)&t4;
                const float* wa = (const float*)&w4;
#pragma unroll
                for (int cp = 0; cp < 2; ++cp) {
                    const v2f r  = { __builtin_amdgcn_rcpf(sa[2*cp]),
                                     __builtin_amdgcn_rcpf(sa[2*cp+1]) };
                    const v2f tt = { ta[2*cp], ta[2*cp+1] };
                    const v2f ww = { wa[2*cp], wa[2*cp+1] };
                    rk[cp]  = r * K;
                    tkn[cp] = -(tt * rk[cp]);
                    wk[cp]  = ww * iK;
                }
            }

            const float* xk = xb + i;
#pragma unroll
            for (int cp = 0; cp < 2; ++cp) {
                v2f u[TB], me[TB];
                // pass 1: LDS reads (ds_read_b64, imm offsets) + u, m for all 8 rows
#pragma unroll
                for (int j = 0; j < TB; ++j) {
                    const v2f x2 = *(const v2f*)(xk + j * I_SZ + 2 * cp);
                    u[j]  = __builtin_elementwise_fma(x2, rk[cp], tkn[cp]); // z*K
                    me[j] = u[j] * (-u[j]);                                 // -(z*K)^2
                }
                __builtin_amdgcn_sched_barrier(0);
                // pass 2: 16 back-to-back trans-pipe exps
#pragma unroll
                for (int j = 0; j < TB; ++j) {
                    me[j].x = __builtin_amdgcn_exp2f(me[j].x);              // exp(-z^2/2)
                    me[j].y = __builtin_amdgcn_exp2f(me[j].y);
                }
                __builtin_amdgcn_sched_barrier(0);
                // pass 3: consumers
#pragma unroll
                for (int j = 0; j < TB; ++j) {
                    const v2f y = u[j] * wk[cp];                            // w*z
                    acc[j] = __builtin_elementwise_fma(-y, me[j], acc[j]);  // += -w*z*e
                }
            }
        }

        // collapse pairs, reduce across the 32 i-split lanes
        float r[TB];
#pragma unroll
        for (int j = 0; j < TB; ++j) r[j] = acc[j].x + acc[j].y;
#pragma unroll
        for (int m = 1; m < SLN; m <<= 1)
#pragma unroll
            for (int j = 0; j < TB; ++j)
                r[j] += __shfl_xor(r[j], m, 64);

        if (sl < TB) {
            float v = 0.0f;
#pragma unroll
            for (int j = 0; j < TB; ++j)
                if (sl == j) v = r[j];
            Out[(size_t)(b0 + sl) * O_SZ + (obase + oi * 8)] = v;
        }
    }
}

extern "C" void kernel_launch(void* const* d_in, const int* in_sizes, int n_in,
                              void* d_out, int out_size, void* d_ws, size_t ws_size,
                              hipStream_t stream) {
    const float* x = (const float*)d_in[0];   // (B, I)
    const float* w = (const float*)d_in[1];   // (O, I)
    const float* s = (const float*)d_in[2];   // (O, I)
    const float* t = (const float*)d_in[3];   // (O, I)
    float* out = (float*)d_out;               // (B, O)

    dim3 grid(O_SZ / (8 * OITER), B_SZ / TB); // (32, 32) = 1024 blocks = 4/CU resident
    wavkan_dog_kernel<<<grid, NTHR, 0, stream>>>(x, w, s, t, out);
}

// Round 5
// 109.430 us; speedup vs baseline: 1.1643x; 1.0093x over previous
//
#include <hip/hip_runtime.h>

// x (B,I); w/s/t (O,I); out (B,O), all fp32.
#define B_SZ 256
#define O_SZ 1024
#define I_SZ 1024

#define TB   8     // b rows per block (LDS x tile)
#define SLN  32    // lanes per half splitting i
#define KITERS (I_SZ / (SLN * 4))   // 8
#define ISTEP  (SLN * 4)            // 128
#define OITER  4                    // o-groups per block (32 o's/block)
#define NTHR 256

typedef float v2f __attribute__((ext_vector_type(2)));

// out[b,o] = sum_i w[o,i]*phi((x[b,i]-t[o,i])/s[o,i]),  phi(z) = -z*exp(-0.5 z^2)
// u = K*(x-t)/s, K = sqrt(0.5*log2 e) -> exp2(-u^2) = exp(-z^2/2);  w*z = u*(w/K)
//
// R13 post-mortem: exp-result clustering changed NOTHING (56.0us). Busy fit is
// exact across R9/R12/R13: 82K cyc/SIMD = 8.2K pk-VALU x2 + 4096 wave-exps x
// 16.0 cyc -> wave64 v_exp_f32 occupies the issue port 16 cyc; port-demand
// floor 34us. The 22us idle is NOT occupancy (R12) and NOT exp latency (R13).
// Remaining suspects: per-phase LDS-read entry bubbles (~120cyc ds latency,
// read consumed immediately, 64 phase entries, waves lockstep) + marginal
// 1-deep global prefetch. R13 also showed 8.4M LDS bank-conflict cycles cost
// ZERO wall time -> LDS pipe has slack; b64 conflicts are free.
// R14: register-rotated x prefetch. Phase(cp0) computes from pre-loaded xr0
// while ISSUING xr1's b64 reads; phase(cp1) computes from xr1 while issuing
// next-k's xr0. Every ds_read gets a full exp cluster (~256cyc) between issue
// and use. k-loop unroll 1 (register-lifetime control). Spill gate: WRITE_SIZE
// ~1.1-1.3MB. Predicted 47-52us if entry bubbles were the idle; unchanged =>
// attack busy floor next (precompute rk/tkn/wk via pre-kernel into d_ws).
__launch_bounds__(NTHR, 4)
__global__ void wavkan_dog_kernel(const float* __restrict__ X,
                                  const float* __restrict__ W,
                                  const float* __restrict__ S,
                                  const float* __restrict__ T,
                                  float* __restrict__ Out) {
    const int tid  = threadIdx.x;
    const int wave = tid >> 6;
    const int lane = tid & 63;
    const int half = lane >> 5;
    const int sl   = lane & (SLN - 1);

    const int obase = blockIdx.x * (8 * OITER) + wave * 2 + half; // + oi*8
    const int b0    = blockIdx.y * TB;

    __shared__ __align__(16) float xls[TB * I_SZ];     // 32 KB

    const int r0 = obase * I_SZ + sl * 4;  // 32-bit offsets, same for W/S/T
    const float* wr = W + r0;
    const float* sr = S + r0;
    const float* tr = T + r0;

    // Issue first w/s/t prefetch BEFORE the LDS fill so it flies under the barrier.
    float4 sN = *(const float4*)(sr);
    float4 tN = *(const float4*)(tr);
    float4 wN = *(const float4*)(wr);

    {   // cooperative fill: x[b0:b0+8][:] is one contiguous 32 KB span
        const float4* Xg4 = (const float4*)(X + (size_t)b0 * I_SZ);
        float4* L4 = (float4*)xls;
#pragma unroll
        for (int p = 0; p < (TB * I_SZ / 4) / NTHR; ++p)
            L4[tid + p * NTHR] = Xg4[tid + p * NTHR];
    }
    __syncthreads();

    const float K  = 0.84932180028801904272f;  // sqrt(0.5 * log2 e)
    const float iK = 1.17741002251547469101f;  // 1/K
    const float* xb = xls + sl * 4;

    // steady-state rotation: xr0 holds cp=0 data for the k-iter about to run
    v2f xr0[TB];
#pragma unroll
    for (int j = 0; j < TB; ++j)
        xr0[j] = *(const v2f*)(xb + j * I_SZ);           // k=0, cp=0

#pragma unroll 1
    for (int oi = 0; oi < OITER; ++oi) {
        const int ob = oi * 8 * I_SZ;          // element offset to this o-group's rows

        v2f acc[TB];
#pragma unroll
        for (int j = 0; j < TB; ++j) acc[j] = (v2f)(0.0f);

#pragma unroll 1
        for (int k = 0; k < KITERS; ++k) {
            const int i = k * ISTEP;
            // prefetch k+1; at k==7 prefetch the NEXT o-group's k=0 (wraps to oi=0: L1-hot, harmless)
            const int in = (k < KITERS - 1) ? (ob + (k + 1) * ISTEP)
                                            : ((((oi + 1) & (OITER - 1)) * 8) * I_SZ);

            const float4 s4 = sN, t4 = tN, w4 = wN;
            sN = *(const float4*)(sr + in);
            tN = *(const float4*)(tr + in);
            wN = *(const float4*)(wr + in);

            v2f rk[2], tkn[2], wk[2];
            {
                const float* sa = (const float*)&s4;
                const float* ta = (const float*)&t4;
                const float* wa = (const float*)&w4;
#pragma unroll
                for (int cp = 0; cp < 2; ++cp) {
                    const v2f r  = { __builtin_amdgcn_rcpf(sa[2*cp]),
                                     __builtin_amdgcn_rcpf(sa[2*cp+1]) };
                    const v2f tt = { ta[2*cp], ta[2*cp+1] };
                    const v2f ww = { wa[2*cp], wa[2*cp+1] };
                    rk[cp]  = r * K;
                    tkn[cp] = -(tt * rk[cp]);
                    wk[cp]  = ww * iK;
                }
            }

            const float* xk  = xb + i;
            // LDS source for next k's cp=0 (at k==KITERS-1 wrap to k=0: same data
            // next oi needs -> rotation stays valid across the oi boundary)
            const float* xkn = xb + ((k < KITERS - 1) ? (i + ISTEP) : 0);

            v2f xr1[TB];

            // ================= phase cp = 0 =================
            {
                v2f u[TB], me[TB];
#pragma unroll
                for (int j = 0; j < TB; ++j) {
                    u[j]  = __builtin_elementwise_fma(xr0[j], rk[0], tkn[0]);
                    me[j] = u[j] * (-u[j]);
                }
                // issue next phase's reads under the exp cluster
#pragma unroll
                for (int j = 0; j < TB; ++j)
                    xr1[j] = *(const v2f*)(xk + j * I_SZ + 2);
                __builtin_amdgcn_sched_barrier(0);
#pragma unroll
                for (int j = 0; j < TB; ++j) {
                    me[j].x = __builtin_amdgcn_exp2f(me[j].x);
                    me[j].y = __builtin_amdgcn_exp2f(me[j].y);
                }
                __builtin_amdgcn_sched_barrier(0);
#pragma unroll
                for (int j = 0; j < TB; ++j) {
                    const v2f y = u[j] * wk[0];
                    acc[j] = __builtin_elementwise_fma(-y, me[j], acc[j]);
                }
            }

            // ================= phase cp = 1 =================
            {
                v2f u[TB], me[TB];
#pragma unroll
                for (int j = 0; j < TB; ++j) {
                    u[j]  = __builtin_elementwise_fma(xr1[j], rk[1], tkn[1]);
                    me[j] = u[j] * (-u[j]);
                }
                // issue next k's cp=0 reads under the exp cluster
#pragma unroll
                for (int j = 0; j < TB; ++j)
                    xr0[j] = *(const v2f*)(xkn + j * I_SZ);
                __builtin_amdgcn_sched_barrier(0);
#pragma unroll
                for (int j = 0; j < TB; ++j) {
                    me[j].x = __builtin_amdgcn_exp2f(me[j].x);
                    me[j].y = __builtin_amdgcn_exp2f(me[j].y);
                }
                __builtin_amdgcn_sched_barrier(0);
#pragma unroll
                for (int j = 0; j < TB; ++j) {
                    const v2f y = u[j] * wk[1];
                    acc[j] = __builtin_elementwise_fma(-y, me[j], acc[j]);
                }
            }
        }

        // collapse pairs, reduce across the 32 i-split lanes
        float r[TB];
#pragma unroll
        for (int j = 0; j < TB; ++j) r[j] = acc[j].x + acc[j].y;
#pragma unroll
        for (int m = 1; m < SLN; m <<= 1)
#pragma unroll
            for (int j = 0; j < TB; ++j)
                r[j] += __shfl_xor(r[j], m, 64);

        if (sl < TB) {
            float v = 0.0f;
#pragma unroll
            for (int j = 0; j < TB; ++j)
                if (sl == j) v = r[j];
            Out[(size_t)(b0 + sl) * O_SZ + (obase + oi * 8)] = v;
        }
    }
}

extern "C" void kernel_launch(void* const* d_in, const int* in_sizes, int n_in,
                              void* d_out, int out_size, void* d_ws, size_t ws_size,
                              hipStream_t stream) {
    const float* x = (const float*)d_in[0];   // (B, I)
    const float* w = (const float*)d_in[1];   // (O, I)
    const float* s = (const float*)d_in[2];   // (O, I)
    const float* t = (const float*)d_in[3];   // (O, I)
    float* out = (float*)d_out;               // (B, O)

    dim3 grid(O_SZ / (8 * OITER), B_SZ / TB); // (32, 32) = 1024 blocks = 4/CU resident
    wavkan_dog_kernel<<<grid, NTHR, 0, stream>>>(x, w, s, t, out);
}

// Round 6
// 108.682 us; speedup vs baseline: 1.1723x; 1.0069x over previous
//
#include <hip/hip_runtime.h>

// x (B,I); w/s/t (O,I); out (B,O), all fp32.
#define B_SZ 256
#define O_SZ 1024
#define I_SZ 1024

#define TB   8     // b rows per block (LDS x tile)
#define SLN  32    // lanes per half splitting i
#define KITERS (I_SZ / (SLN * 4))   // 8
#define ISTEP  (SLN * 4)            // 128
#define OITER  4                    // o-groups per block (32 o's/block)
#define NTHR 256

typedef float v2f __attribute__((ext_vector_type(2)));

// out[b,o] = sum_i w[o,i]*phi((x[b,i]-t[o,i])/s[o,i]),  phi(z) = -z*exp(-0.5 z^2)
// u = K*(x-t)/s, K = sqrt(0.5*log2 e) -> exp2(-u^2) = exp(-z^2/2);  w*z = u*(w/K)
//
// R14 post-mortem: x-read rotation won 2.6us (56.0->53.4) -- phase-entry LDS
// bubbles were real but small. Busy floor stable at ~34us (port-hold model:
// wave64 v_exp occupies issue ~16cyc; demand irreducible without changing the
// exp path). Remaining ~20us idle: the last in-place producer->consumer knot
// is the k-iter top: vmcnt wait for w/s/t -> 4 dependent rcps (trans lat) ->
// rk->tkn chain -> first fma, hit by all waves in lockstep.
// R15: pipeline loads 2-deep (ping-pong La/Lb) and prep 1 k-iter ahead
// (ping-pong P0/P1), manual 2x k-unroll (no rotation copies). mk_prep(g+1)
// (vmcnt wait + rcps) sits mid-cp0 of iter g, ~700 issue-cyc from first use.
// R14 phase structure (xr rotation, sched_barrier-pinned exp clusters) kept.
// Spill gate: WRITE_SIZE ~1.1-1.3MB, VGPR 70-90. Predicted 47-50us if the
// k-top knot was the idle; unchanged => structural, roofline-vs-table decision.

struct Ld   { float4 s, t, w; };
struct Prep { v2f rk[2], tkn[2], wk[2]; };

__device__ __forceinline__ int goff(int g) {
    g &= (OITER * KITERS - 1);                 // wrap (tail prefetches loop around)
    return (g >> 3) * (8 * I_SZ) + (g & 7) * ISTEP;
}

__device__ __forceinline__ void issue_ld(Ld& L, const float* sr, const float* tr,
                                         const float* wr, int off) {
    L.s = *(const float4*)(sr + off);
    L.t = *(const float4*)(tr + off);
    L.w = *(const float4*)(wr + off);
}

__device__ __forceinline__ void mk_prep(Prep& P, const Ld& L,
                                        float K, float iK) {
    const float* sa = (const float*)&L.s;
    const float* ta = (const float*)&L.t;
    const float* wa = (const float*)&L.w;
#pragma unroll
    for (int cp = 0; cp < 2; ++cp) {
        const v2f r  = { __builtin_amdgcn_rcpf(sa[2*cp]),
                         __builtin_amdgcn_rcpf(sa[2*cp+1]) };
        const v2f tt = { ta[2*cp], ta[2*cp+1] };
        const v2f ww = { wa[2*cp], wa[2*cp+1] };
        P.rk[cp]  = r * K;
        P.tkn[cp] = -(tt * P.rk[cp]);
        P.wk[cp]  = ww * iK;
    }
}

// One k-step. Entry invariants: Pc = prep(g); Lprep holds loads(g+1) (in
// flight or landed); Lissue's loads(g) are already consumed (prep'd last
// body) -> safe to overwrite with loads(g+2). Writes Pn = prep(g+1).
__device__ __forceinline__ void body(int g,
    const float* sr, const float* tr, const float* wr, const float* xb,
    Ld& Lissue, const Ld& Lprep, const Prep& Pc, Prep& Pn,
    v2f xr0[TB], v2f acc[TB], float K, float iK)
{
    const int k = g & 7;
    const float* xk  = xb + k * ISTEP;
    const float* xkn = xb + ((k + 1) & 7) * ISTEP;   // wraps across oi: same tile

    issue_ld(Lissue, sr, tr, wr, goff(g + 2));       // 2-deep global prefetch

    v2f xr1[TB];

    // ================= phase cp = 0 =================
    {
        v2f u[TB], me[TB];
#pragma unroll
        for (int j = 0; j < TB; ++j) {
            u[j]  = __builtin_elementwise_fma(xr0[j], Pc.rk[0], Pc.tkn[0]);
            me[j] = u[j] * (-u[j]);
        }
        // issue next phase's x reads under the exp cluster
#pragma unroll
        for (int j = 0; j < TB; ++j)
            xr1[j] = *(const v2f*)(xk + j * I_SZ + 2);
        // prep for g+1: vmcnt wait + rcps land HERE, far from their use
        mk_prep(Pn, Lprep, K, iK);
        __builtin_amdgcn_sched_barrier(0);
#pragma unroll
        for (int j = 0; j < TB; ++j) {
            me[j].x = __builtin_amdgcn_exp2f(me[j].x);
            me[j].y = __builtin_amdgcn_exp2f(me[j].y);
        }
        __builtin_amdgcn_sched_barrier(0);
#pragma unroll
        for (int j = 0; j < TB; ++j) {
            const v2f y = u[j] * Pc.wk[0];
            acc[j] = __builtin_elementwise_fma(-y, me[j], acc[j]);
        }
    }

    // ================= phase cp = 1 =================
    {
        v2f u[TB], me[TB];
#pragma unroll
        for (int j = 0; j < TB; ++j) {
            u[j]  = __builtin_elementwise_fma(xr1[j], Pc.rk[1], Pc.tkn[1]);
            me[j] = u[j] * (-u[j]);
        }
        // issue next k's cp=0 reads under the exp cluster
#pragma unroll
        for (int j = 0; j < TB; ++j)
            xr0[j] = *(const v2f*)(xkn + j * I_SZ);
        __builtin_amdgcn_sched_barrier(0);
#pragma unroll
        for (int j = 0; j < TB; ++j) {
            me[j].x = __builtin_amdgcn_exp2f(me[j].x);
            me[j].y = __builtin_amdgcn_exp2f(me[j].y);
        }
        __builtin_amdgcn_sched_barrier(0);
#pragma unroll
        for (int j = 0; j < TB; ++j) {
            const v2f y = u[j] * Pc.wk[1];
            acc[j] = __builtin_elementwise_fma(-y, me[j], acc[j]);
        }
    }
}

__launch_bounds__(NTHR, 4)
__global__ void wavkan_dog_kernel(const float* __restrict__ X,
                                  const float* __restrict__ W,
                                  const float* __restrict__ S,
                                  const float* __restrict__ T,
                                  float* __restrict__ Out) {
    const int tid  = threadIdx.x;
    const int wave = tid >> 6;
    const int lane = tid & 63;
    const int half = lane >> 5;
    const int sl   = lane & (SLN - 1);

    const int obase = blockIdx.x * (8 * OITER) + wave * 2 + half; // + oi*8
    const int b0    = blockIdx.y * TB;

    __shared__ __align__(16) float xls[TB * I_SZ];     // 32 KB

    const int r0 = obase * I_SZ + sl * 4;  // 32-bit offsets, same for W/S/T
    const float* wr = W + r0;
    const float* sr = S + r0;
    const float* tr = T + r0;

    // Fill the load pipeline BEFORE the LDS fill so it flies under the barrier.
    Ld La, Lb;
    issue_ld(La, sr, tr, wr, goff(0));
    issue_ld(Lb, sr, tr, wr, goff(1));

    {   // cooperative fill: x[b0:b0+8][:] is one contiguous 32 KB span
        const float4* Xg4 = (const float4*)(X + (size_t)b0 * I_SZ);
        float4* L4 = (float4*)xls;
#pragma unroll
        for (int p = 0; p < (TB * I_SZ / 4) / NTHR; ++p)
            L4[tid + p * NTHR] = Xg4[tid + p * NTHR];
    }
    __syncthreads();

    const float K  = 0.84932180028801904272f;  // sqrt(0.5 * log2 e)
    const float iK = 1.17741002251547469101f;  // 1/K
    const float* xb = xls + sl * 4;

    Prep P0, P1;
    mk_prep(P0, La, K, iK);                    // prep for g=0 (partial vmcnt wait)

    // steady-state rotation: xr0 holds cp=0 data for the k-iter about to run
    v2f xr0[TB];
#pragma unroll
    for (int j = 0; j < TB; ++j)
        xr0[j] = *(const v2f*)(xb + j * I_SZ);           // k=0, cp=0

#pragma unroll 1
    for (int oi = 0; oi < OITER; ++oi) {
        v2f acc[TB];
#pragma unroll
        for (int j = 0; j < TB; ++j) acc[j] = (v2f)(0.0f);

#pragma unroll 1
        for (int kk = 0; kk < KITERS / 2; ++kk) {
            const int g = oi * KITERS + kk * 2;
            // even: overwrite La (held loads g, consumed), prep from Lb (g+1)
            body(g,     sr, tr, wr, xb, La, Lb, P0, P1, xr0, acc, K, iK);
            // odd: overwrite Lb (held g+1, consumed), prep from La (g+2)
            body(g + 1, sr, tr, wr, xb, Lb, La, P1, P0, xr0, acc, K, iK);
        }

        // collapse pairs, reduce across the 32 i-split lanes
        float r[TB];
#pragma unroll
        for (int j = 0; j < TB; ++j) r[j] = acc[j].x + acc[j].y;
#pragma unroll
        for (int m = 1; m < SLN; m <<= 1)
#pragma unroll
            for (int j = 0; j < TB; ++j)
                r[j] += __shfl_xor(r[j], m, 64);

        if (sl < TB) {
            float v = 0.0f;
#pragma unroll
            for (int j = 0; j < TB; ++j)
                if (sl == j) v = r[j];
            Out[(size_t)(b0 + sl) * O_SZ + (obase + oi * 8)] = v;
        }
    }
}

extern "C" void kernel_launch(void* const* d_in, const int* in_sizes, int n_in,
                              void* d_out, int out_size, void* d_ws, size_t ws_size,
                              hipStream_t stream) {
    const float* x = (const float*)d_in[0];   // (B, I)
    const float* w = (const float*)d_in[1];   // (O, I)
    const float* s = (const float*)d_in[2];   // (O, I)
    const float* t = (const float*)d_in[3];   // (O, I)
    float* out = (float*)d_out;               // (B, O)

    dim3 grid(O_SZ / (8 * OITER), B_SZ / TB); // (32, 32) = 1024 blocks = 4/CU resident
    wavkan_dog_kernel<<<grid, NTHR, 0, stream>>>(x, w, s, t, out);
}